// Round 1
// 932.556 us; speedup vs baseline: 1.1648x; 1.1648x over previous
//
#include <hip/hip_runtime.h>

// HGRN BitMLP (all I/O float32):
//   x[8192,2048] -> bitlinear(w_gate[16384,2048]) -> silu(gate)*v
//   -> bitlinear(w_down[2048,8192]) -> out[8192,2048]
// Int8 activations x ternary weights -> mfma_i32_16x16x64_i8.
// v2: GEMMs rewritten as double-buffered 2-phase pipeline (stage next tile
// before computing current, ONE barrier per K-step whose implicit vmcnt(0)
// drains the prefetch), wave tile grown to 64x64(x2) / 64x128 so LDS-read
// arithmetic intensity rises 32 -> 42.7 MACs/byte. Fragment-order LDS slabs
// kept (zero bank conflicts).

using char8  = __attribute__((ext_vector_type(8))) signed char;
using int4v  = __attribute__((ext_vector_type(4))) int;
using half8  = __attribute__((ext_vector_type(8))) _Float16;

// async global->LDS, 16B per lane; LDS dest = wave-uniform base + lane*16
__device__ __forceinline__ void glds16(const void* g, void* l) {
  __builtin_amdgcn_global_load_lds((const __attribute__((address_space(1))) void*)g,
                                   (__attribute__((address_space(3))) void*)l, 16, 0, 0);
}

// ---------------- deterministic sum(|w|) reduction (f32 input) --------------
__global__ __launch_bounds__(256) void reduce_abs_kernel(
    const float4* __restrict__ w, float* __restrict__ partials, int n4) {
  int t = threadIdx.x;
  int gid = blockIdx.x * 256 + t;
  int stride = gridDim.x * 256;
  float s = 0.f;
  for (int i = gid; i < n4; i += stride) {
    float4 u = w[i];
    s += fabsf(u.x) + fabsf(u.y) + fabsf(u.z) + fabsf(u.w);
  }
  __shared__ float sm[256];
  sm[t] = s; __syncthreads();
  for (int off = 128; off > 0; off >>= 1) {
    if (t < off) sm[t] += sm[t + off];
    __syncthreads();
  }
  if (t == 0) partials[blockIdx.x] = sm[0];
}

__global__ __launch_bounds__(256) void finalize_kernel(
    const float* __restrict__ pf, float* __restrict__ scales) {
  __shared__ float sm[256];
  int t = threadIdx.x;
  float s = pf[t] + pf[t + 256] + pf[t + 512] + pf[t + 768];
  sm[t] = s; __syncthreads();
  for (int off = 128; off > 0; off >>= 1) {
    if (t < off) sm[t] += sm[t + off];
    __syncthreads();
  }
  if (t == 0) {  // w_gate: 16384*2048 elements
    float c = fmaxf(sm[0] / 33554432.0f, 1e-5f);
    scales[0] = c; scales[2] = 1.0f / c;
  }
  __syncthreads();
  s = pf[1024 + t] + pf[1280 + t] + pf[1536 + t] + pf[1792 + t];
  sm[t] = s; __syncthreads();
  for (int off = 128; off > 0; off >>= 1) {
    if (t < off) sm[t] += sm[t + off];
    __syncthreads();
  }
  if (t == 0) {  // w_down: 2048*8192 elements
    float c = fmaxf(sm[0] / 16777216.0f, 1e-5f);
    scales[1] = c; scales[3] = 1.0f / c;
  }
}

// ------- ternary weight quant: f32 in -> {-1,0,1} int8 --------
__global__ __launch_bounds__(256) void quant_weight_kernel(
    const float4* __restrict__ w, char8* __restrict__ wq,
    const float* __restrict__ invp, int n8) {
  float inv = *invp;  // 1/clip(mean|w|,1e-5)
  int stride = gridDim.x * 256;
  for (int i = blockIdx.x * 256 + threadIdx.x; i < n8; i += stride) {
    float4 a = w[2 * i], b = w[2 * i + 1];
    float v[8] = {a.x, a.y, a.z, a.w, b.x, b.y, b.z, b.w};
    char8 o;
#pragma unroll
    for (int j = 0; j < 8; ++j) {
      float q = rintf(v[j] * inv);
      q = fminf(fmaxf(q, -1.f), 1.f);
      o[j] = (signed char)(int)q;
    }
    wq[i] = o;
  }
}

// ------- per-token RMSNorm + absmax int8 quant, f32 input (row = 2048) -------
__global__ __launch_bounds__(256) void act_quant_f32_kernel(
    const float* __restrict__ in, signed char* __restrict__ out,
    float* __restrict__ fscale) {
  const int token = blockIdx.x, t = threadIdx.x;
  const float4* row = (const float4*)(in + (size_t)token * 2048);
  float4 a = row[2 * t], b = row[2 * t + 1];
  float v[8] = {a.x, a.y, a.z, a.w, b.x, b.y, b.z, b.w};
  float ss = 0.f, am = 0.f;
#pragma unroll
  for (int j = 0; j < 8; ++j) { ss += v[j] * v[j]; am = fmaxf(am, fabsf(v[j])); }
  __shared__ float s1[256], s2[256];
  s1[t] = ss; s2[t] = am; __syncthreads();
  for (int off = 128; off > 0; off >>= 1) {
    if (t < off) { s1[t] += s1[t + off]; s2[t] = fmaxf(s2[t], s2[t + off]); }
    __syncthreads();
  }
  float r = 1.0f / sqrtf(s1[0] * (1.0f / 2048.0f) + 1e-8f);  // rsqrt(mean+RMS_EPS)
  float f = fmaxf(s2[0] * r, 1e-5f);                          // clip(max|xn|,Q_EPS)
  float s = 127.0f / f;
  if (t == 0) fscale[token] = f * (1.0f / 127.0f);            // dequant factor
  char8 o;
#pragma unroll
  for (int j = 0; j < 8; ++j) {
    float q = rintf((v[j] * r) * s);
    q = fminf(fmaxf(q, -128.f), 127.f);
    o[j] = (signed char)(int)q;
  }
  ((char8*)(out + (size_t)token * 2048))[t] = o;
}

// ------- per-token RMSNorm + absmax int8 quant, fp16 input (row = 8192) -----
__global__ __launch_bounds__(256) void act_quant_h_kernel(
    const _Float16* __restrict__ in, signed char* __restrict__ out,
    float* __restrict__ fscale) {
  const int token = blockIdx.x, t = threadIdx.x;
  const half8* row = (const half8*)(in + (size_t)token * 8192);
  float v[32];
  float ss = 0.f, am = 0.f;
#pragma unroll
  for (int c = 0; c < 4; ++c) {
    half8 u = row[c * 256 + t];
#pragma unroll
    for (int j = 0; j < 8; ++j) {
      float f = (float)u[j]; v[c * 8 + j] = f;
      ss += f * f; am = fmaxf(am, fabsf(f));
    }
  }
  __shared__ float s1[256], s2[256];
  s1[t] = ss; s2[t] = am; __syncthreads();
  for (int off = 128; off > 0; off >>= 1) {
    if (t < off) { s1[t] += s1[t + off]; s2[t] = fmaxf(s2[t], s2[t + off]); }
    __syncthreads();
  }
  float r = 1.0f / sqrtf(s1[0] * (1.0f / 8192.0f) + 1e-8f);
  float f = fmaxf(s2[0] * r, 1e-5f);
  float s = 127.0f / f;
  if (t == 0) fscale[token] = f * (1.0f / 127.0f);
#pragma unroll
  for (int c = 0; c < 4; ++c) {
    char8 o;
#pragma unroll
    for (int j = 0; j < 8; ++j) {
      float q = rintf((v[c * 8 + j] * r) * s);
      q = fminf(fmaxf(q, -128.f), 127.f);
      o[j] = (signed char)(int)q;
    }
    ((char8*)(out + (size_t)token * 8192))[c * 256 + t] = o;
  }
}

// ---------------- GEMM1: z = silu(Xq@WgT[:I]) * (Xq@WgT[I:]) ----------------
// block: 128 tokens x 128 z-cols; 4 waves in 2x2, each wave 64x64 z
// (gate + value accumulators). BK=64, double-buffered LDS (2 x 24KB),
// prefetch-next-then-compute-current, one barrier per K-step.
// Fragment-order slabs: slab u (1024B) slot l = row u*16+(l&15),
// bytes (l>>4)*16..+15 -> frag read = base + l*16 (no bank conflicts).
__global__ __launch_bounds__(256, 2) void gemm1_kernel(
    const signed char* __restrict__ A,  // xq [8192,2048] i8
    const signed char* __restrict__ B,  // wgq [16384,2048] i8 ternary
    const float* __restrict__ f1, const float* __restrict__ cgp,
    _Float16* __restrict__ Z) {         // z fp16 [8192,8192]
  constexpr int K = 2048, I = 8192, NT = K / 64;
  constexpr int BUF = 24576;            // 8KB A + 16KB B per stage
  __shared__ __align__(16) signed char Ls[2 * BUF];
  const int t0 = blockIdx.y * 128, n0 = blockIdx.x * 128;
  const int tid = threadIdx.x, w = tid >> 6, l = tid & 63;
  const int wm = (w >> 1) * 64, wn = (w & 1) * 64;
  const int lrow = l & 15, lchunk = (l >> 4) * 16;

  int4v ag[4][4], av[4][4];
#pragma unroll
  for (int i = 0; i < 4; ++i)
#pragma unroll
    for (int j = 0; j < 4; ++j) { ag[i][j] = {0,0,0,0}; av[i][j] = {0,0,0,0}; }

  // staging: 24 slabs (A:0..7, B gate:8..15, B value:16..23), wave w owns 6
  const signed char* src[6];
  int dst[6];
#pragma unroll
  for (int r = 0; r < 6; ++r) {
    int u = w * 6 + r;
    if (u < 8) {                        // A slab u
      src[r] = A + (size_t)(t0 + u * 16 + lrow) * K + lchunk;
      dst[r] = u * 1024;
    } else {                            // B slab v
      int v = u - 8;
      int grow = (v < 8) ? (n0 + v * 16 + lrow) : (I + n0 + (v - 8) * 16 + lrow);
      src[r] = B + (size_t)grow * K + lchunk;
      dst[r] = 8192 + v * 1024;
    }
  }

  // prologue: stage tile 0
#pragma unroll
  for (int r = 0; r < 6; ++r) glds16(src[r], &Ls[dst[r]]);
  __syncthreads();

  const int aoff = (wm >> 4) * 1024 + l * 16;
  const int goff = 8192 + (wn >> 4) * 1024 + l * 16;
  const int voff = goff + 8 * 1024;

#pragma unroll 2
  for (int it = 0; it < NT; ++it) {
    const int cur = (it & 1) * BUF;
    const int nxt = BUF - cur;
    if (it + 1 < NT) {                  // stage NEXT tile before computing
      const int ko = (it + 1) * 64;
#pragma unroll
      for (int r = 0; r < 6; ++r) glds16(src[r] + ko, &Ls[nxt + dst[r]]);
    }
    int4v af[4], bg[4], bv[4];
#pragma unroll
    for (int i = 0; i < 4; ++i) af[i] = *(const int4v*)&Ls[cur + aoff + i * 1024];
#pragma unroll
    for (int j = 0; j < 4; ++j) {
      bg[j] = *(const int4v*)&Ls[cur + goff + j * 1024];
      bv[j] = *(const int4v*)&Ls[cur + voff + j * 1024];
    }
#pragma unroll
    for (int i = 0; i < 4; ++i)
#pragma unroll
      for (int j = 0; j < 4; ++j) {
        ag[i][j] = __builtin_amdgcn_mfma_i32_16x16x64_i8(af[i], bg[j], ag[i][j], 0, 0, 0);
        av[i][j] = __builtin_amdgcn_mfma_i32_16x16x64_i8(af[i], bv[j], av[i][j], 0, 0, 0);
      }
    __syncthreads();                    // drains vmcnt: tile it+1 ready, buffers safe
  }

  float cg = *cgp;
#pragma unroll
  for (int i = 0; i < 4; ++i)
#pragma unroll
    for (int rr = 0; rr < 4; ++rr) {
      int m = wm + i * 16 + (l >> 4) * 4 + rr;
      float fs = f1[t0 + m] * cg;
#pragma unroll
      for (int j = 0; j < 4; ++j) {
        int n = wn + j * 16 + (l & 15);
        float g = (float)ag[i][j][rr] * fs, vv = (float)av[i][j][rr] * fs;
        float z = g / (1.0f + __expf(-g)) * vv;  // silu(g)*v
        Z[(size_t)(t0 + m) * I + n0 + n] = (_Float16)z;
      }
    }
}

// ---------------- GEMM2: out = (Zq @ WdT) * f2 * cd  (f32 output) ----------
// block: 128 tokens x 256 out-cols; 4 waves in 2x2, each wave 64x128.
// Same double-buffered 2-phase pipeline as gemm1.
__global__ __launch_bounds__(256, 2) void gemm2_kernel(
    const signed char* __restrict__ A,  // zq [8192,8192] i8
    const signed char* __restrict__ B,  // wdq [2048,8192] i8 ternary
    const float* __restrict__ f2, const float* __restrict__ cdp,
    float* __restrict__ out) {          // [8192,2048] f32
  constexpr int K = 8192, N = 2048, NT = K / 64;
  constexpr int BUF = 24576;            // 8KB A + 16KB B per stage
  __shared__ __align__(16) signed char Ls[2 * BUF];
  const int t0 = blockIdx.y * 128, n0 = blockIdx.x * 256;
  const int tid = threadIdx.x, w = tid >> 6, l = tid & 63;
  const int wm = (w >> 1) * 64, wn = (w & 1) * 128;
  const int lrow = l & 15, lchunk = (l >> 4) * 16;

  int4v acc[4][8];
#pragma unroll
  for (int i = 0; i < 4; ++i)
#pragma unroll
    for (int j = 0; j < 8; ++j) acc[i][j] = {0,0,0,0};

  // staging: 24 slabs (A:0..7, B:8..23), wave w owns 6
  const signed char* src[6];
  int dst[6];
#pragma unroll
  for (int r = 0; r < 6; ++r) {
    int u = w * 6 + r;
    if (u < 8) {                        // A slab u
      src[r] = A + (size_t)(t0 + u * 16 + lrow) * K + lchunk;
      dst[r] = u * 1024;
    } else {                            // B slab v
      int v = u - 8;
      src[r] = B + (size_t)(n0 + v * 16 + lrow) * K + lchunk;
      dst[r] = 8192 + v * 1024;
    }
  }

  // prologue: stage tile 0
#pragma unroll
  for (int r = 0; r < 6; ++r) glds16(src[r], &Ls[dst[r]]);
  __syncthreads();

  const int aoff = (wm >> 4) * 1024 + l * 16;
  const int boff = 8192 + (wn >> 4) * 1024 + l * 16;

#pragma unroll 2
  for (int it = 0; it < NT; ++it) {
    const int cur = (it & 1) * BUF;
    const int nxt = BUF - cur;
    if (it + 1 < NT) {
      const int ko = (it + 1) * 64;
#pragma unroll
      for (int r = 0; r < 6; ++r) glds16(src[r] + ko, &Ls[nxt + dst[r]]);
    }
    int4v af[4], bf[8];
#pragma unroll
    for (int i = 0; i < 4; ++i) af[i] = *(const int4v*)&Ls[cur + aoff + i * 1024];
#pragma unroll
    for (int j = 0; j < 8; ++j) bf[j] = *(const int4v*)&Ls[cur + boff + j * 1024];
#pragma unroll
    for (int i = 0; i < 4; ++i)
#pragma unroll
      for (int j = 0; j < 8; ++j)
        acc[i][j] = __builtin_amdgcn_mfma_i32_16x16x64_i8(af[i], bf[j], acc[i][j], 0, 0, 0);
    __syncthreads();
  }

  float cd = *cdp;
#pragma unroll
  for (int i = 0; i < 4; ++i)
#pragma unroll
    for (int rr = 0; rr < 4; ++rr) {
      int m = wm + i * 16 + (l >> 4) * 4 + rr;
      float fs = f2[t0 + m] * cd;
#pragma unroll
      for (int j = 0; j < 8; ++j) {
        int n = wn + j * 16 + (l & 15);
        out[(size_t)(t0 + m) * N + n0 + n] = (float)acc[i][j][rr] * fs;
      }
    }
}

extern "C" void kernel_launch(void* const* d_in, const int* in_sizes, int n_in,
                              void* d_out, int out_size, void* d_ws, size_t ws_size,
                              hipStream_t stream) {
  const float* x  = (const float*)d_in[0];  // [8192,2048] f32
  const float* wg = (const float*)d_in[1];  // [16384,2048] f32
  const float* wd = (const float*)d_in[2];  // [2048,8192] f32
  float* out = (float*)d_out;               // [8192,2048] f32

  // workspace layout (~268.5 MB)
  char* ws = (char*)d_ws;
  signed char* wgq = (signed char*)(ws);                 //  33,554,432 B
  signed char* wdq = (signed char*)(ws + 33554432);      //  16,777,216 B
  signed char* xq  = (signed char*)(ws + 50331648);      //  16,777,216 B
  signed char* zq  = (signed char*)(ws + 67108864);      //  67,108,864 B
  _Float16*    z   = (_Float16*)  (ws + 134217728);      // 134,217,728 B
  float* f1     = (float*)(ws + 268435456);              //      32,768 B
  float* f2     = (float*)(ws + 268468224);              //      32,768 B
  float* pf     = (float*)(ws + 268500992);              //       8,192 B
  float* scales = (float*)(ws + 268509184);              //          16 B

  // 1) global mean(|w|) for both weight matrices (deterministic, no atomics)
  reduce_abs_kernel<<<1024, 256, 0, stream>>>((const float4*)wg, pf, 8388608);
  reduce_abs_kernel<<<1024, 256, 0, stream>>>((const float4*)wd, pf + 1024, 4194304);
  finalize_kernel<<<1, 256, 0, stream>>>(pf, scales);

  // 2) ternarize weights, int8-quantize activations
  quant_weight_kernel<<<2048, 256, 0, stream>>>((const float4*)wg, (char8*)wgq, scales + 2, 4194304);
  quant_weight_kernel<<<1024, 256, 0, stream>>>((const float4*)wd, (char8*)wdq, scales + 3, 2097152);
  act_quant_f32_kernel<<<8192, 256, 0, stream>>>(x, xq, f1);

  // 3) GEMM1 (i8) fused with dequant + silu*v -> z (fp16)
  gemm1_kernel<<<dim3(64, 64), 256, 0, stream>>>(xq, wgq, f1, scales, z);

  // 4) quantize z -> zq (i8) + f2
  act_quant_h_kernel<<<8192, 256, 0, stream>>>(z, zq, f2);

  // 5) GEMM2 (i8) fused with dequant -> out (f32)
  gemm2_kernel<<<dim3(8, 64), 256, 0, stream>>>(zq, wdq, f2, scales + 1, out);
}

// Round 2
// 911.139 us; speedup vs baseline: 1.1922x; 1.0235x over previous
//
#include <hip/hip_runtime.h>

// HGRN BitMLP (all I/O float32):
//   x[8192,2048] -> bitlinear(w_gate[16384,2048]) -> silu(gate)*v
//   -> bitlinear(w_down[2048,8192]) -> out[8192,2048]
// Int8 activations x ternary weights -> mfma_i32_16x16x64_i8.
// v3: 3-buffer pipeline with COUNTED vmcnt (T4): stage tile it+3 into the
// freed buffer, wait vmcnt(12) so only tile it+1 (issued 2 iters ago) must
// have landed -- loads stay in flight across barriers, no vmcnt(0) drain in
// the main loop. Raw s_barrier x2 per step. setprio(1) around MFMA (T5).
// Fragment-order LDS slabs kept (zero bank conflicts).

using char8  = __attribute__((ext_vector_type(8))) signed char;
using int4v  = __attribute__((ext_vector_type(4))) int;
using half8  = __attribute__((ext_vector_type(8))) _Float16;

// async global->LDS, 16B per lane; LDS dest = wave-uniform base + lane*16
__device__ __forceinline__ void glds16(const void* g, void* l) {
  __builtin_amdgcn_global_load_lds((const __attribute__((address_space(1))) void*)g,
                                   (__attribute__((address_space(3))) void*)l, 16, 0, 0);
}

// ---------------- deterministic sum(|w|) reduction (f32 input) --------------
__global__ __launch_bounds__(256) void reduce_abs_kernel(
    const float4* __restrict__ w, float* __restrict__ partials, int n4) {
  int t = threadIdx.x;
  int gid = blockIdx.x * 256 + t;
  int stride = gridDim.x * 256;
  float s = 0.f;
  for (int i = gid; i < n4; i += stride) {
    float4 u = w[i];
    s += fabsf(u.x) + fabsf(u.y) + fabsf(u.z) + fabsf(u.w);
  }
  __shared__ float sm[256];
  sm[t] = s; __syncthreads();
  for (int off = 128; off > 0; off >>= 1) {
    if (t < off) sm[t] += sm[t + off];
    __syncthreads();
  }
  if (t == 0) partials[blockIdx.x] = sm[0];
}

__global__ __launch_bounds__(256) void finalize_kernel(
    const float* __restrict__ pf, float* __restrict__ scales) {
  __shared__ float sm[256];
  int t = threadIdx.x;
  float s = pf[t] + pf[t + 256] + pf[t + 512] + pf[t + 768];
  sm[t] = s; __syncthreads();
  for (int off = 128; off > 0; off >>= 1) {
    if (t < off) sm[t] += sm[t + off];
    __syncthreads();
  }
  if (t == 0) {  // w_gate: 16384*2048 elements
    float c = fmaxf(sm[0] / 33554432.0f, 1e-5f);
    scales[0] = c; scales[2] = 1.0f / c;
  }
  __syncthreads();
  s = pf[1024 + t] + pf[1280 + t] + pf[1536 + t] + pf[1792 + t];
  sm[t] = s; __syncthreads();
  for (int off = 128; off > 0; off >>= 1) {
    if (t < off) sm[t] += sm[t + off];
    __syncthreads();
  }
  if (t == 0) {  // w_down: 2048*8192 elements
    float c = fmaxf(sm[0] / 16777216.0f, 1e-5f);
    scales[1] = c; scales[3] = 1.0f / c;
  }
}

// ------- ternary weight quant: f32 in -> {-1,0,1} int8 --------
__global__ __launch_bounds__(256) void quant_weight_kernel(
    const float4* __restrict__ w, char8* __restrict__ wq,
    const float* __restrict__ invp, int n8) {
  float inv = *invp;  // 1/clip(mean|w|,1e-5)
  int stride = gridDim.x * 256;
  for (int i = blockIdx.x * 256 + threadIdx.x; i < n8; i += stride) {
    float4 a = w[2 * i], b = w[2 * i + 1];
    float v[8] = {a.x, a.y, a.z, a.w, b.x, b.y, b.z, b.w};
    char8 o;
#pragma unroll
    for (int j = 0; j < 8; ++j) {
      float q = rintf(v[j] * inv);
      q = fminf(fmaxf(q, -1.f), 1.f);
      o[j] = (signed char)(int)q;
    }
    wq[i] = o;
  }
}

// ------- per-token RMSNorm + absmax int8 quant, f32 input (row = 2048) -------
__global__ __launch_bounds__(256) void act_quant_f32_kernel(
    const float* __restrict__ in, signed char* __restrict__ out,
    float* __restrict__ fscale) {
  const int token = blockIdx.x, t = threadIdx.x;
  const float4* row = (const float4*)(in + (size_t)token * 2048);
  float4 a = row[2 * t], b = row[2 * t + 1];
  float v[8] = {a.x, a.y, a.z, a.w, b.x, b.y, b.z, b.w};
  float ss = 0.f, am = 0.f;
#pragma unroll
  for (int j = 0; j < 8; ++j) { ss += v[j] * v[j]; am = fmaxf(am, fabsf(v[j])); }
  __shared__ float s1[256], s2[256];
  s1[t] = ss; s2[t] = am; __syncthreads();
  for (int off = 128; off > 0; off >>= 1) {
    if (t < off) { s1[t] += s1[t + off]; s2[t] = fmaxf(s2[t], s2[t + off]); }
    __syncthreads();
  }
  float r = 1.0f / sqrtf(s1[0] * (1.0f / 2048.0f) + 1e-8f);  // rsqrt(mean+RMS_EPS)
  float f = fmaxf(s2[0] * r, 1e-5f);                          // clip(max|xn|,Q_EPS)
  float s = 127.0f / f;
  if (t == 0) fscale[token] = f * (1.0f / 127.0f);            // dequant factor
  char8 o;
#pragma unroll
  for (int j = 0; j < 8; ++j) {
    float q = rintf((v[j] * r) * s);
    q = fminf(fmaxf(q, -128.f), 127.f);
    o[j] = (signed char)(int)q;
  }
  ((char8*)(out + (size_t)token * 2048))[t] = o;
}

// ------- per-token RMSNorm + absmax int8 quant, fp16 input (row = 8192) -----
__global__ __launch_bounds__(256) void act_quant_h_kernel(
    const _Float16* __restrict__ in, signed char* __restrict__ out,
    float* __restrict__ fscale) {
  const int token = blockIdx.x, t = threadIdx.x;
  const half8* row = (const half8*)(in + (size_t)token * 8192);
  float v[32];
  float ss = 0.f, am = 0.f;
#pragma unroll
  for (int c = 0; c < 4; ++c) {
    half8 u = row[c * 256 + t];
#pragma unroll
    for (int j = 0; j < 8; ++j) {
      float f = (float)u[j]; v[c * 8 + j] = f;
      ss += f * f; am = fmaxf(am, fabsf(f));
    }
  }
  __shared__ float s1[256], s2[256];
  s1[t] = ss; s2[t] = am; __syncthreads();
  for (int off = 128; off > 0; off >>= 1) {
    if (t < off) { s1[t] += s1[t + off]; s2[t] = fmaxf(s2[t], s2[t + off]); }
    __syncthreads();
  }
  float r = 1.0f / sqrtf(s1[0] * (1.0f / 8192.0f) + 1e-8f);
  float f = fmaxf(s2[0] * r, 1e-5f);
  float s = 127.0f / f;
  if (t == 0) fscale[token] = f * (1.0f / 127.0f);
#pragma unroll
  for (int c = 0; c < 4; ++c) {
    char8 o;
#pragma unroll
    for (int j = 0; j < 8; ++j) {
      float q = rintf((v[c * 8 + j] * r) * s);
      q = fminf(fmaxf(q, -128.f), 127.f);
      o[j] = (signed char)(int)q;
    }
    ((char8*)(out + (size_t)token * 8192))[c * 256 + t] = o;
  }
}

// ---------------- GEMM1: z = silu(Xq@WgT[:I]) * (Xq@WgT[I:]) ----------------
// block: 128 tokens x 128 z-cols; 4 waves in 2x2, each wave 64x64 z
// (gate + value accumulators). BK=64, 3-buffer LDS (3 x 24KB), counted-vmcnt
// pipeline: at the sync point only tile it+1 (issued 2 iters ago) must have
// landed -> s_waitcnt vmcnt(12), never 0 in steady state.
// Fragment-order slabs: slab u (1024B) slot l = row u*16+(l&15),
// bytes (l>>4)*16..+15 -> frag read = base + l*16 (no bank conflicts).
__global__ __launch_bounds__(256, 2) void gemm1_kernel(
    const signed char* __restrict__ A,  // xq [8192,2048] i8
    const signed char* __restrict__ B,  // wgq [16384,2048] i8 ternary
    const float* __restrict__ f1, const float* __restrict__ cgp,
    _Float16* __restrict__ Z) {         // z fp16 [8192,8192]
  constexpr int K = 2048, I = 8192, NT = K / 64;
  constexpr int BUF = 24576;            // 8KB A + 16KB B per stage
  __shared__ __align__(16) signed char Ls[3 * BUF];
  const int t0 = blockIdx.y * 128, n0 = blockIdx.x * 128;
  const int tid = threadIdx.x, w = tid >> 6, l = tid & 63;
  const int wm = (w >> 1) * 64, wn = (w & 1) * 64;
  const int lrow = l & 15, lchunk = (l >> 4) * 16;

  int4v ag[4][4], av[4][4];
#pragma unroll
  for (int i = 0; i < 4; ++i)
#pragma unroll
    for (int j = 0; j < 4; ++j) { ag[i][j] = {0,0,0,0}; av[i][j] = {0,0,0,0}; }

  // staging: 24 slabs (A:0..7, B gate:8..15, B value:16..23), wave w owns 6
  const signed char* src[6];
  int dst[6];
#pragma unroll
  for (int r = 0; r < 6; ++r) {
    int u = w * 6 + r;
    if (u < 8) {                        // A slab u
      src[r] = A + (size_t)(t0 + u * 16 + lrow) * K + lchunk;
      dst[r] = u * 1024;
    } else {                            // B slab v
      int v = u - 8;
      int grow = (v < 8) ? (n0 + v * 16 + lrow) : (I + n0 + (v - 8) * 16 + lrow);
      src[r] = B + (size_t)grow * K + lchunk;
      dst[r] = 8192 + v * 1024;
    }
  }

  // prologue: stage tiles 0,1,2 (18 loads in flight), publish tile 0
#pragma unroll
  for (int p = 0; p < 3; ++p)
#pragma unroll
    for (int r = 0; r < 6; ++r) glds16(src[r] + p * 64, &Ls[p * BUF + dst[r]]);
  asm volatile("s_waitcnt vmcnt(12)" ::: "memory");  // tile 0 landed
  __builtin_amdgcn_s_barrier();
  __builtin_amdgcn_sched_barrier(0);

  const int aoff = (wm >> 4) * 1024 + l * 16;
  const int goff = 8192 + (wn >> 4) * 1024 + l * 16;
  const int voff = goff + 8 * 1024;

  int curo = 0;
  for (int it = 0; it < NT; ++it) {
    int4v af[4], bg[4], bv[4];
#pragma unroll
    for (int i = 0; i < 4; ++i) af[i] = *(const int4v*)&Ls[curo + aoff + i * 1024];
#pragma unroll
    for (int j = 0; j < 4; ++j) {
      bg[j] = *(const int4v*)&Ls[curo + goff + j * 1024];
      bv[j] = *(const int4v*)&Ls[curo + voff + j * 1024];
    }
    __builtin_amdgcn_s_setprio(1);
#pragma unroll
    for (int i = 0; i < 4; ++i)
#pragma unroll
      for (int j = 0; j < 4; ++j) {
        ag[i][j] = __builtin_amdgcn_mfma_i32_16x16x64_i8(af[i], bg[j], ag[i][j], 0, 0, 0);
        av[i][j] = __builtin_amdgcn_mfma_i32_16x16x64_i8(af[i], bv[j], av[i][j], 0, 0, 0);
      }
    __builtin_amdgcn_s_setprio(0);
    if (it + 3 < NT) {                  // restage freed buffer with tile it+3
      __builtin_amdgcn_s_barrier();     // all waves done reading buf[cur]
      __builtin_amdgcn_sched_barrier(0);
#pragma unroll
      for (int r = 0; r < 6; ++r) glds16(src[r] + (it + 3) * 64, &Ls[curo + dst[r]]);
    }
    // wait so tile it+1 (oldest 6 outstanding) has landed; keep rest in flight
    if (it < NT - 3)        asm volatile("s_waitcnt vmcnt(12)" ::: "memory");
    else if (it == NT - 3)  asm volatile("s_waitcnt vmcnt(6)" ::: "memory");
    else if (it == NT - 2)  asm volatile("s_waitcnt vmcnt(0)" ::: "memory");
    if (it + 1 < NT) {
      __builtin_amdgcn_s_barrier();     // publish buf[nxt] block-wide
      __builtin_amdgcn_sched_barrier(0);
    }
    curo += BUF; if (curo == 3 * BUF) curo = 0;
  }

  float cg = *cgp;
#pragma unroll
  for (int i = 0; i < 4; ++i)
#pragma unroll
    for (int rr = 0; rr < 4; ++rr) {
      int m = wm + i * 16 + (l >> 4) * 4 + rr;
      float fs = f1[t0 + m] * cg;
#pragma unroll
      for (int j = 0; j < 4; ++j) {
        int n = wn + j * 16 + (l & 15);
        float g = (float)ag[i][j][rr] * fs, vv = (float)av[i][j][rr] * fs;
        float z = g / (1.0f + __expf(-g)) * vv;  // silu(g)*v
        Z[(size_t)(t0 + m) * I + n0 + n] = (_Float16)z;
      }
    }
}

// ---------------- GEMM2: out = (Zq @ WdT) * f2 * cd  (f32 output) ----------
// block: 128 tokens x 256 out-cols; 4 waves in 2x2, each wave 64x128.
// Same 3-buffer counted-vmcnt pipeline as gemm1.
__global__ __launch_bounds__(256, 2) void gemm2_kernel(
    const signed char* __restrict__ A,  // zq [8192,8192] i8
    const signed char* __restrict__ B,  // wdq [2048,8192] i8 ternary
    const float* __restrict__ f2, const float* __restrict__ cdp,
    float* __restrict__ out) {          // [8192,2048] f32
  constexpr int K = 8192, N = 2048, NT = K / 64;
  constexpr int BUF = 24576;            // 8KB A + 16KB B per stage
  __shared__ __align__(16) signed char Ls[3 * BUF];
  const int t0 = blockIdx.y * 128, n0 = blockIdx.x * 256;
  const int tid = threadIdx.x, w = tid >> 6, l = tid & 63;
  const int wm = (w >> 1) * 64, wn = (w & 1) * 128;
  const int lrow = l & 15, lchunk = (l >> 4) * 16;

  int4v acc[4][8];
#pragma unroll
  for (int i = 0; i < 4; ++i)
#pragma unroll
    for (int j = 0; j < 8; ++j) acc[i][j] = {0,0,0,0};

  // staging: 24 slabs (A:0..7, B:8..23), wave w owns 6
  const signed char* src[6];
  int dst[6];
#pragma unroll
  for (int r = 0; r < 6; ++r) {
    int u = w * 6 + r;
    if (u < 8) {                        // A slab u
      src[r] = A + (size_t)(t0 + u * 16 + lrow) * K + lchunk;
      dst[r] = u * 1024;
    } else {                            // B slab v
      int v = u - 8;
      src[r] = B + (size_t)(n0 + v * 16 + lrow) * K + lchunk;
      dst[r] = 8192 + v * 1024;
    }
  }

  // prologue: stage tiles 0,1,2
#pragma unroll
  for (int p = 0; p < 3; ++p)
#pragma unroll
    for (int r = 0; r < 6; ++r) glds16(src[r] + p * 64, &Ls[p * BUF + dst[r]]);
  asm volatile("s_waitcnt vmcnt(12)" ::: "memory");
  __builtin_amdgcn_s_barrier();
  __builtin_amdgcn_sched_barrier(0);

  const int aoff = (wm >> 4) * 1024 + l * 16;
  const int boff = 8192 + (wn >> 4) * 1024 + l * 16;

  int curo = 0;
  for (int it = 0; it < NT; ++it) {
    int4v af[4], bf[8];
#pragma unroll
    for (int i = 0; i < 4; ++i) af[i] = *(const int4v*)&Ls[curo + aoff + i * 1024];
#pragma unroll
    for (int j = 0; j < 8; ++j) bf[j] = *(const int4v*)&Ls[curo + boff + j * 1024];
    __builtin_amdgcn_s_setprio(1);
#pragma unroll
    for (int i = 0; i < 4; ++i)
#pragma unroll
      for (int j = 0; j < 8; ++j)
        acc[i][j] = __builtin_amdgcn_mfma_i32_16x16x64_i8(af[i], bf[j], acc[i][j], 0, 0, 0);
    __builtin_amdgcn_s_setprio(0);
    if (it + 3 < NT) {
      __builtin_amdgcn_s_barrier();
      __builtin_amdgcn_sched_barrier(0);
#pragma unroll
      for (int r = 0; r < 6; ++r) glds16(src[r] + (it + 3) * 64, &Ls[curo + dst[r]]);
    }
    if (it < NT - 3)        asm volatile("s_waitcnt vmcnt(12)" ::: "memory");
    else if (it == NT - 3)  asm volatile("s_waitcnt vmcnt(6)" ::: "memory");
    else if (it == NT - 2)  asm volatile("s_waitcnt vmcnt(0)" ::: "memory");
    if (it + 1 < NT) {
      __builtin_amdgcn_s_barrier();
      __builtin_amdgcn_sched_barrier(0);
    }
    curo += BUF; if (curo == 3 * BUF) curo = 0;
  }

  float cd = *cdp;
#pragma unroll
  for (int i = 0; i < 4; ++i)
#pragma unroll
    for (int rr = 0; rr < 4; ++rr) {
      int m = wm + i * 16 + (l >> 4) * 4 + rr;
      float fs = f2[t0 + m] * cd;
#pragma unroll
      for (int j = 0; j < 8; ++j) {
        int n = wn + j * 16 + (l & 15);
        out[(size_t)(t0 + m) * N + n0 + n] = (float)acc[i][j][rr] * fs;
      }
    }
}

extern "C" void kernel_launch(void* const* d_in, const int* in_sizes, int n_in,
                              void* d_out, int out_size, void* d_ws, size_t ws_size,
                              hipStream_t stream) {
  const float* x  = (const float*)d_in[0];  // [8192,2048] f32
  const float* wg = (const float*)d_in[1];  // [16384,2048] f32
  const float* wd = (const float*)d_in[2];  // [2048,8192] f32
  float* out = (float*)d_out;               // [8192,2048] f32

  // workspace layout (~268.5 MB)
  char* ws = (char*)d_ws;
  signed char* wgq = (signed char*)(ws);                 //  33,554,432 B
  signed char* wdq = (signed char*)(ws + 33554432);      //  16,777,216 B
  signed char* xq  = (signed char*)(ws + 50331648);      //  16,777,216 B
  signed char* zq  = (signed char*)(ws + 67108864);      //  67,108,864 B
  _Float16*    z   = (_Float16*)  (ws + 134217728);      // 134,217,728 B
  float* f1     = (float*)(ws + 268435456);              //      32,768 B
  float* f2     = (float*)(ws + 268468224);              //      32,768 B
  float* pf     = (float*)(ws + 268500992);              //       8,192 B
  float* scales = (float*)(ws + 268509184);              //          16 B

  // 1) global mean(|w|) for both weight matrices (deterministic, no atomics)
  reduce_abs_kernel<<<1024, 256, 0, stream>>>((const float4*)wg, pf, 8388608);
  reduce_abs_kernel<<<1024, 256, 0, stream>>>((const float4*)wd, pf + 1024, 4194304);
  finalize_kernel<<<1, 256, 0, stream>>>(pf, scales);

  // 2) ternarize weights, int8-quantize activations
  quant_weight_kernel<<<2048, 256, 0, stream>>>((const float4*)wg, (char8*)wgq, scales + 2, 4194304);
  quant_weight_kernel<<<1024, 256, 0, stream>>>((const float4*)wd, (char8*)wdq, scales + 3, 2097152);
  act_quant_f32_kernel<<<8192, 256, 0, stream>>>(x, xq, f1);

  // 3) GEMM1 (i8) fused with dequant + silu*v -> z (fp16)
  gemm1_kernel<<<dim3(64, 64), 256, 0, stream>>>(xq, wgq, f1, scales, z);

  // 4) quantize z -> zq (i8) + f2
  act_quant_h_kernel<<<8192, 256, 0, stream>>>(z, zq, f2);

  // 5) GEMM2 (i8) fused with dequant -> out (f32)
  gemm2_kernel<<<dim3(8, 64), 256, 0, stream>>>(zq, wdq, f2, scales + 1, out);
}

// Round 3
// 902.803 us; speedup vs baseline: 1.2032x; 1.0092x over previous
//
#include <hip/hip_runtime.h>

// HGRN BitMLP (all I/O float32):
//   x[8192,2048] -> bitlinear(w_gate[16384,2048]) -> silu(gate)*v
//   -> bitlinear(w_down[2048,8192]) -> out[8192,2048]
// Int8 activations x ternary weights -> mfma_i32_16x16x64_i8.
// v4: 8-phase-style interleave (T3): each K64 step split into 4 phases
// {ds_read phase frags | 2x glds16 stage | barrier | 8 MFMA (setprio) |
// barrier} so the LDS read stream of phase p+1 hides under the MFMA drain
// of phase p. 3-buffer LDS, counted vmcnt(6) at tile boundary only (T4),
// staging spread across phases (depth-2 prefetch). Fragment-order slabs
// (zero bank conflicts).

using char8  = __attribute__((ext_vector_type(8))) signed char;
using int4v  = __attribute__((ext_vector_type(4))) int;
using half8  = __attribute__((ext_vector_type(8))) _Float16;

// async global->LDS, 16B per lane; LDS dest = wave-uniform base + lane*16
__device__ __forceinline__ void glds16(const void* g, void* l) {
  __builtin_amdgcn_global_load_lds((const __attribute__((address_space(1))) void*)g,
                                   (__attribute__((address_space(3))) void*)l, 16, 0, 0);
}

#define SB0() __builtin_amdgcn_sched_barrier(0)

// ---------------- deterministic sum(|w|) reduction (f32 input) --------------
__global__ __launch_bounds__(256) void reduce_abs_kernel(
    const float4* __restrict__ w, float* __restrict__ partials, int n4) {
  int t = threadIdx.x;
  int gid = blockIdx.x * 256 + t;
  int stride = gridDim.x * 256;
  float s = 0.f;
  for (int i = gid; i < n4; i += stride) {
    float4 u = w[i];
    s += fabsf(u.x) + fabsf(u.y) + fabsf(u.z) + fabsf(u.w);
  }
  __shared__ float sm[256];
  sm[t] = s; __syncthreads();
  for (int off = 128; off > 0; off >>= 1) {
    if (t < off) sm[t] += sm[t + off];
    __syncthreads();
  }
  if (t == 0) partials[blockIdx.x] = sm[0];
}

__global__ __launch_bounds__(256) void finalize_kernel(
    const float* __restrict__ pf, float* __restrict__ scales) {
  __shared__ float sm[256];
  int t = threadIdx.x;
  float s = pf[t] + pf[t + 256] + pf[t + 512] + pf[t + 768];
  sm[t] = s; __syncthreads();
  for (int off = 128; off > 0; off >>= 1) {
    if (t < off) sm[t] += sm[t + off];
    __syncthreads();
  }
  if (t == 0) {  // w_gate: 16384*2048 elements
    float c = fmaxf(sm[0] / 33554432.0f, 1e-5f);
    scales[0] = c; scales[2] = 1.0f / c;
  }
  __syncthreads();
  s = pf[1024 + t] + pf[1280 + t] + pf[1536 + t] + pf[1792 + t];
  sm[t] = s; __syncthreads();
  for (int off = 128; off > 0; off >>= 1) {
    if (t < off) sm[t] += sm[t + off];
    __syncthreads();
  }
  if (t == 0) {  // w_down: 2048*8192 elements
    float c = fmaxf(sm[0] / 16777216.0f, 1e-5f);
    scales[1] = c; scales[3] = 1.0f / c;
  }
}

// ------- ternary weight quant: f32 in -> {-1,0,1} int8 --------
__global__ __launch_bounds__(256) void quant_weight_kernel(
    const float4* __restrict__ w, char8* __restrict__ wq,
    const float* __restrict__ invp, int n8) {
  float inv = *invp;  // 1/clip(mean|w|,1e-5)
  int stride = gridDim.x * 256;
  for (int i = blockIdx.x * 256 + threadIdx.x; i < n8; i += stride) {
    float4 a = w[2 * i], b = w[2 * i + 1];
    float v[8] = {a.x, a.y, a.z, a.w, b.x, b.y, b.z, b.w};
    char8 o;
#pragma unroll
    for (int j = 0; j < 8; ++j) {
      float q = rintf(v[j] * inv);
      q = fminf(fmaxf(q, -1.f), 1.f);
      o[j] = (signed char)(int)q;
    }
    wq[i] = o;
  }
}

// ------- per-token RMSNorm + absmax int8 quant, f32 input (row = 2048) -------
__global__ __launch_bounds__(256) void act_quant_f32_kernel(
    const float* __restrict__ in, signed char* __restrict__ out,
    float* __restrict__ fscale) {
  const int token = blockIdx.x, t = threadIdx.x;
  const float4* row = (const float4*)(in + (size_t)token * 2048);
  float4 a = row[2 * t], b = row[2 * t + 1];
  float v[8] = {a.x, a.y, a.z, a.w, b.x, b.y, b.z, b.w};
  float ss = 0.f, am = 0.f;
#pragma unroll
  for (int j = 0; j < 8; ++j) { ss += v[j] * v[j]; am = fmaxf(am, fabsf(v[j])); }
  __shared__ float s1[256], s2[256];
  s1[t] = ss; s2[t] = am; __syncthreads();
  for (int off = 128; off > 0; off >>= 1) {
    if (t < off) { s1[t] += s1[t + off]; s2[t] = fmaxf(s2[t], s2[t + off]); }
    __syncthreads();
  }
  float r = 1.0f / sqrtf(s1[0] * (1.0f / 2048.0f) + 1e-8f);  // rsqrt(mean+RMS_EPS)
  float f = fmaxf(s2[0] * r, 1e-5f);                          // clip(max|xn|,Q_EPS)
  float s = 127.0f / f;
  if (t == 0) fscale[token] = f * (1.0f / 127.0f);            // dequant factor
  char8 o;
#pragma unroll
  for (int j = 0; j < 8; ++j) {
    float q = rintf((v[j] * r) * s);
    q = fminf(fmaxf(q, -128.f), 127.f);
    o[j] = (signed char)(int)q;
  }
  ((char8*)(out + (size_t)token * 2048))[t] = o;
}

// ------- per-token RMSNorm + absmax int8 quant, fp16 input (row = 8192) -----
__global__ __launch_bounds__(256) void act_quant_h_kernel(
    const _Float16* __restrict__ in, signed char* __restrict__ out,
    float* __restrict__ fscale) {
  const int token = blockIdx.x, t = threadIdx.x;
  const half8* row = (const half8*)(in + (size_t)token * 8192);
  float v[32];
  float ss = 0.f, am = 0.f;
#pragma unroll
  for (int c = 0; c < 4; ++c) {
    half8 u = row[c * 256 + t];
#pragma unroll
    for (int j = 0; j < 8; ++j) {
      float f = (float)u[j]; v[c * 8 + j] = f;
      ss += f * f; am = fmaxf(am, fabsf(f));
    }
  }
  __shared__ float s1[256], s2[256];
  s1[t] = ss; s2[t] = am; __syncthreads();
  for (int off = 128; off > 0; off >>= 1) {
    if (t < off) { s1[t] += s1[t + off]; s2[t] = fmaxf(s2[t], s2[t + off]); }
    __syncthreads();
  }
  float r = 1.0f / sqrtf(s1[0] * (1.0f / 8192.0f) + 1e-8f);
  float f = fmaxf(s2[0] * r, 1e-5f);
  float s = 127.0f / f;
  if (t == 0) fscale[token] = f * (1.0f / 127.0f);
#pragma unroll
  for (int c = 0; c < 4; ++c) {
    char8 o;
#pragma unroll
    for (int j = 0; j < 8; ++j) {
      float q = rintf((v[c * 8 + j] * r) * s);
      q = fminf(fmaxf(q, -128.f), 127.f);
      o[j] = (signed char)(int)q;
    }
    ((char8*)(out + (size_t)token * 8192))[c * 256 + t] = o;
  }
}

// ---------------- GEMM1: z = silu(Xq@WgT[:I]) * (Xq@WgT[I:]) ----------------
// block: 128 tokens x 128 z-cols; 4 waves in 2x2, each wave 64x64 z
// (gate + value accumulators). BK=64, 3-buffer LDS, 4-phase interleave per
// K-step; counted vmcnt(6) at tile boundary (stage depth 2).
// Fragment-order slabs: slab u (1024B) slot l = row u*16+(l&15),
// bytes (l>>4)*16..+15 -> frag read = base + l*16 (no bank conflicts).
__global__ __launch_bounds__(256, 2) void gemm1_kernel(
    const signed char* __restrict__ A,  // xq [8192,2048] i8
    const signed char* __restrict__ B,  // wgq [16384,2048] i8 ternary
    const float* __restrict__ f1, const float* __restrict__ cgp,
    _Float16* __restrict__ Z) {         // z fp16 [8192,8192]
  constexpr int K = 2048, I = 8192, NT = K / 64;
  constexpr int BUF = 24576;            // 8KB A + 16KB B per stage
  __shared__ __align__(16) signed char Ls[3 * BUF];
  const int t0 = blockIdx.y * 128, n0 = blockIdx.x * 128;
  const int tid = threadIdx.x, w = tid >> 6, l = tid & 63;
  const int wm = (w >> 1) * 64, wn = (w & 1) * 64;
  const int lrow = l & 15, lchunk = (l >> 4) * 16;

  int4v ag[4][4], av[4][4];
#pragma unroll
  for (int i = 0; i < 4; ++i)
#pragma unroll
    for (int j = 0; j < 4; ++j) { ag[i][j] = {0,0,0,0}; av[i][j] = {0,0,0,0}; }

  // staging: 24 slabs (A:0..7, B gate:8..15, B value:16..23), wave w owns 6
  const signed char* src[6];
  int dst[6];
#pragma unroll
  for (int r = 0; r < 6; ++r) {
    int u = w * 6 + r;
    if (u < 8) {                        // A slab u
      src[r] = A + (size_t)(t0 + u * 16 + lrow) * K + lchunk;
      dst[r] = u * 1024;
    } else {                            // B slab v
      int v = u - 8;
      int grow = (v < 8) ? (n0 + v * 16 + lrow) : (I + n0 + (v - 8) * 16 + lrow);
      src[r] = B + (size_t)grow * K + lchunk;
      dst[r] = 8192 + v * 1024;
    }
  }

  // prologue: stage tiles 0 and 1 (12 loads in flight), publish tile 0
#pragma unroll
  for (int p = 0; p < 2; ++p)
#pragma unroll
    for (int r = 0; r < 6; ++r) glds16(src[r] + p * 64, &Ls[p * BUF + dst[r]]);
  asm volatile("s_waitcnt vmcnt(6)" ::: "memory");  // tile 0 landed
  __builtin_amdgcn_s_barrier();
  SB0();

  const int aoff = (wm >> 4) * 1024 + l * 16;
  const int goff = 8192 + (wn >> 4) * 1024 + l * 16;
  const int voff = goff + 8 * 1024;

  int curo = 0;
  for (int it = 0; it < NT; ++it) {
    int stgo = curo + 2 * BUF; if (stgo >= 3 * BUF) stgo -= 3 * BUF;
    const bool stg = (it + 2 < NT);
    const int ko = (it + 2) * 64;
    int4v af[4], bg[4], bv[4];

#pragma unroll
    for (int j = 0; j < 4; ++j) {
      // ---- phase j: reads (+af on j==0), stage 2 slabs (j<3), 8 MFMA ----
      if (j == 0) {
#pragma unroll
        for (int i = 0; i < 4; ++i) af[i] = *(const int4v*)&Ls[curo + aoff + i * 1024];
      }
      bg[j] = *(const int4v*)&Ls[curo + goff + j * 1024];
      bv[j] = *(const int4v*)&Ls[curo + voff + j * 1024];
      if (stg && j < 3) {
        glds16(src[2 * j] + ko, &Ls[stgo + dst[2 * j]]);
        glds16(src[2 * j + 1] + ko, &Ls[stgo + dst[2 * j + 1]]);
      }
      SB0();
      __builtin_amdgcn_s_barrier();
      SB0();
      __builtin_amdgcn_s_setprio(1);
#pragma unroll
      for (int i = 0; i < 4; ++i)
        ag[i][j] = __builtin_amdgcn_mfma_i32_16x16x64_i8(af[i], bg[j], ag[i][j], 0, 0, 0);
#pragma unroll
      for (int i = 0; i < 4; ++i)
        av[i][j] = __builtin_amdgcn_mfma_i32_16x16x64_i8(af[i], bv[j], av[i][j], 0, 0, 0);
      __builtin_amdgcn_s_setprio(0);
      SB0();
      if (j < 3) {
        __builtin_amdgcn_s_barrier();
        SB0();
      }
    }
    // ---- tile boundary: counted wait (tile it+1 landed), publish ----
    if (it < NT - 2)       asm volatile("s_waitcnt vmcnt(6)" ::: "memory");
    else if (it == NT - 2) asm volatile("s_waitcnt vmcnt(0)" ::: "memory");
    if (it + 1 < NT) {
      __builtin_amdgcn_s_barrier();
      SB0();
    }
    curo += BUF; if (curo == 3 * BUF) curo = 0;
  }

  float cg = *cgp;
#pragma unroll
  for (int i = 0; i < 4; ++i)
#pragma unroll
    for (int rr = 0; rr < 4; ++rr) {
      int m = wm + i * 16 + (l >> 4) * 4 + rr;
      float fs = f1[t0 + m] * cg;
#pragma unroll
      for (int j = 0; j < 4; ++j) {
        int n = wn + j * 16 + (l & 15);
        float g = (float)ag[i][j][rr] * fs, vv = (float)av[i][j][rr] * fs;
        float z = g / (1.0f + __expf(-g)) * vv;  // silu(g)*v
        Z[(size_t)(t0 + m) * I + n0 + n] = (_Float16)z;
      }
    }
}

// ---------------- GEMM2: out = (Zq @ WdT) * f2 * cd  (f32 output) ----------
// block: 128 tokens x 256 out-cols; 4 waves in 2x2, each wave 64x128.
// Same 3-buffer 4-phase counted-vmcnt pipeline as gemm1.
__global__ __launch_bounds__(256, 2) void gemm2_kernel(
    const signed char* __restrict__ A,  // zq [8192,8192] i8
    const signed char* __restrict__ B,  // wdq [2048,8192] i8 ternary
    const float* __restrict__ f2, const float* __restrict__ cdp,
    float* __restrict__ out) {          // [8192,2048] f32
  constexpr int K = 8192, N = 2048, NT = K / 64;
  constexpr int BUF = 24576;            // 8KB A + 16KB B per stage
  __shared__ __align__(16) signed char Ls[3 * BUF];
  const int t0 = blockIdx.y * 128, n0 = blockIdx.x * 256;
  const int tid = threadIdx.x, w = tid >> 6, l = tid & 63;
  const int wm = (w >> 1) * 64, wn = (w & 1) * 128;
  const int lrow = l & 15, lchunk = (l >> 4) * 16;

  int4v acc[4][8];
#pragma unroll
  for (int i = 0; i < 4; ++i)
#pragma unroll
    for (int j = 0; j < 8; ++j) acc[i][j] = {0,0,0,0};

  // staging: 24 slabs (A:0..7, B:8..23), wave w owns 6
  const signed char* src[6];
  int dst[6];
#pragma unroll
  for (int r = 0; r < 6; ++r) {
    int u = w * 6 + r;
    if (u < 8) {                        // A slab u
      src[r] = A + (size_t)(t0 + u * 16 + lrow) * K + lchunk;
      dst[r] = u * 1024;
    } else {                            // B slab v
      int v = u - 8;
      src[r] = B + (size_t)(n0 + v * 16 + lrow) * K + lchunk;
      dst[r] = 8192 + v * 1024;
    }
  }

  // prologue: stage tiles 0 and 1
#pragma unroll
  for (int p = 0; p < 2; ++p)
#pragma unroll
    for (int r = 0; r < 6; ++r) glds16(src[r] + p * 64, &Ls[p * BUF + dst[r]]);
  asm volatile("s_waitcnt vmcnt(6)" ::: "memory");
  __builtin_amdgcn_s_barrier();
  SB0();

  const int aoff = (wm >> 4) * 1024 + l * 16;
  const int boff = 8192 + (wn >> 4) * 1024 + l * 16;

  int curo = 0;
  for (int it = 0; it < NT; ++it) {
    int stgo = curo + 2 * BUF; if (stgo >= 3 * BUF) stgo -= 3 * BUF;
    const bool stg = (it + 2 < NT);
    const int ko = (it + 2) * 64;
    int4v af[4], bf[8];

#pragma unroll
    for (int p = 0; p < 4; ++p) {
      // ---- phase p: reads (+af on p==0), stage 2 slabs (p<3), 8 MFMA ----
      if (p == 0) {
#pragma unroll
        for (int i = 0; i < 4; ++i) af[i] = *(const int4v*)&Ls[curo + aoff + i * 1024];
      }
      bf[2 * p]     = *(const int4v*)&Ls[curo + boff + (2 * p) * 1024];
      bf[2 * p + 1] = *(const int4v*)&Ls[curo + boff + (2 * p + 1) * 1024];
      if (stg && p < 3) {
        glds16(src[2 * p] + ko, &Ls[stgo + dst[2 * p]]);
        glds16(src[2 * p + 1] + ko, &Ls[stgo + dst[2 * p + 1]]);
      }
      SB0();
      __builtin_amdgcn_s_barrier();
      SB0();
      __builtin_amdgcn_s_setprio(1);
#pragma unroll
      for (int i = 0; i < 4; ++i)
        acc[i][2 * p] = __builtin_amdgcn_mfma_i32_16x16x64_i8(af[i], bf[2 * p], acc[i][2 * p], 0, 0, 0);
#pragma unroll
      for (int i = 0; i < 4; ++i)
        acc[i][2 * p + 1] = __builtin_amdgcn_mfma_i32_16x16x64_i8(af[i], bf[2 * p + 1], acc[i][2 * p + 1], 0, 0, 0);
      __builtin_amdgcn_s_setprio(0);
      SB0();
      if (p < 3) {
        __builtin_amdgcn_s_barrier();
        SB0();
      }
    }
    // ---- tile boundary ----
    if (it < NT - 2)       asm volatile("s_waitcnt vmcnt(6)" ::: "memory");
    else if (it == NT - 2) asm volatile("s_waitcnt vmcnt(0)" ::: "memory");
    if (it + 1 < NT) {
      __builtin_amdgcn_s_barrier();
      SB0();
    }
    curo += BUF; if (curo == 3 * BUF) curo = 0;
  }

  float cd = *cdp;
#pragma unroll
  for (int i = 0; i < 4; ++i)
#pragma unroll
    for (int rr = 0; rr < 4; ++rr) {
      int m = wm + i * 16 + (l >> 4) * 4 + rr;
      float fs = f2[t0 + m] * cd;
#pragma unroll
      for (int j = 0; j < 8; ++j) {
        int n = wn + j * 16 + (l & 15);
        out[(size_t)(t0 + m) * N + n0 + n] = (float)acc[i][j][rr] * fs;
      }
    }
}

extern "C" void kernel_launch(void* const* d_in, const int* in_sizes, int n_in,
                              void* d_out, int out_size, void* d_ws, size_t ws_size,
                              hipStream_t stream) {
  const float* x  = (const float*)d_in[0];  // [8192,2048] f32
  const float* wg = (const float*)d_in[1];  // [16384,2048] f32
  const float* wd = (const float*)d_in[2];  // [2048,8192] f32
  float* out = (float*)d_out;               // [8192,2048] f32

  // workspace layout (~268.5 MB)
  char* ws = (char*)d_ws;
  signed char* wgq = (signed char*)(ws);                 //  33,554,432 B
  signed char* wdq = (signed char*)(ws + 33554432);      //  16,777,216 B
  signed char* xq  = (signed char*)(ws + 50331648);      //  16,777,216 B
  signed char* zq  = (signed char*)(ws + 67108864);      //  67,108,864 B
  _Float16*    z   = (_Float16*)  (ws + 134217728);      // 134,217,728 B
  float* f1     = (float*)(ws + 268435456);              //      32,768 B
  float* f2     = (float*)(ws + 268468224);              //      32,768 B
  float* pf     = (float*)(ws + 268500992);              //       8,192 B
  float* scales = (float*)(ws + 268509184);              //          16 B

  // 1) global mean(|w|) for both weight matrices (deterministic, no atomics)
  reduce_abs_kernel<<<1024, 256, 0, stream>>>((const float4*)wg, pf, 8388608);
  reduce_abs_kernel<<<1024, 256, 0, stream>>>((const float4*)wd, pf + 1024, 4194304);
  finalize_kernel<<<1, 256, 0, stream>>>(pf, scales);

  // 2) ternarize weights, int8-quantize activations
  quant_weight_kernel<<<2048, 256, 0, stream>>>((const float4*)wg, (char8*)wgq, scales + 2, 4194304);
  quant_weight_kernel<<<1024, 256, 0, stream>>>((const float4*)wd, (char8*)wdq, scales + 3, 2097152);
  act_quant_f32_kernel<<<8192, 256, 0, stream>>>(x, xq, f1);

  // 3) GEMM1 (i8) fused with dequant + silu*v -> z (fp16)
  gemm1_kernel<<<dim3(64, 64), 256, 0, stream>>>(xq, wgq, f1, scales, z);

  // 4) quantize z -> zq (i8) + f2
  act_quant_h_kernel<<<8192, 256, 0, stream>>>(z, zq, f2);

  // 5) GEMM2 (i8) fused with dequant -> out (f32)
  gemm2_kernel<<<dim3(8, 64), 256, 0, stream>>>(zq, wdq, f2, scales + 1, out);
}

// Round 4
// 804.181 us; speedup vs baseline: 1.3508x; 1.1226x over previous
//
#include <hip/hip_runtime.h>

// HGRN BitMLP (all I/O float32):
//   x[8192,2048] -> bitlinear(w_gate[16384,2048]) -> silu(gate)*v
//   -> bitlinear(w_down[2048,8192]) -> out[8192,2048]
// Int8 activations x ternary weights -> mfma_i32_16x16x64_i8.
// v5: m201-template port. BM=256, BK=64, 512 threads / 8 waves (2Mx4N),
// wave tile 128x64. 3x32KB LDS buffers; per wave 4 glds16 per K-tile
// (1 per phase, staging tile it+2); boundary wait vmcnt(4) -- never 0 in
// steady state. Each phase: {ds_read 2 A-frags (+4 B-frags at ph0) | 1 glds
// | barrier | lgkmcnt(0) | setprio(1) 8 MFMA setprio(0) | barrier} so the
// LDS reads of phase p+1 issue while phase p's matrix pipe drains.
// Fragment-order slabs (zero bank conflicts).

using char8  = __attribute__((ext_vector_type(8))) signed char;
using int4v  = __attribute__((ext_vector_type(4))) int;
using half8  = __attribute__((ext_vector_type(8))) _Float16;

// async global->LDS, 16B per lane; LDS dest = wave-uniform base + lane*16
__device__ __forceinline__ void glds16(const void* g, void* l) {
  __builtin_amdgcn_global_load_lds((const __attribute__((address_space(1))) void*)g,
                                   (__attribute__((address_space(3))) void*)l, 16, 0, 0);
}

#define SB0() __builtin_amdgcn_sched_barrier(0)

// ---------------- deterministic sum(|w|) reduction (f32 input) --------------
__global__ __launch_bounds__(256) void reduce_abs_kernel(
    const float4* __restrict__ w, float* __restrict__ partials, int n4) {
  int t = threadIdx.x;
  int gid = blockIdx.x * 256 + t;
  int stride = gridDim.x * 256;
  float s = 0.f;
  for (int i = gid; i < n4; i += stride) {
    float4 u = w[i];
    s += fabsf(u.x) + fabsf(u.y) + fabsf(u.z) + fabsf(u.w);
  }
  __shared__ float sm[256];
  sm[t] = s; __syncthreads();
  for (int off = 128; off > 0; off >>= 1) {
    if (t < off) sm[t] += sm[t + off];
    __syncthreads();
  }
  if (t == 0) partials[blockIdx.x] = sm[0];
}

__global__ __launch_bounds__(256) void finalize_kernel(
    const float* __restrict__ pf, float* __restrict__ scales) {
  __shared__ float sm[256];
  int t = threadIdx.x;
  float s = pf[t] + pf[t + 256] + pf[t + 512] + pf[t + 768];
  sm[t] = s; __syncthreads();
  for (int off = 128; off > 0; off >>= 1) {
    if (t < off) sm[t] += sm[t + off];
    __syncthreads();
  }
  if (t == 0) {  // w_gate: 16384*2048 elements
    float c = fmaxf(sm[0] / 33554432.0f, 1e-5f);
    scales[0] = c; scales[2] = 1.0f / c;
  }
  __syncthreads();
  s = pf[1024 + t] + pf[1280 + t] + pf[1536 + t] + pf[1792 + t];
  sm[t] = s; __syncthreads();
  for (int off = 128; off > 0; off >>= 1) {
    if (t < off) sm[t] += sm[t + off];
    __syncthreads();
  }
  if (t == 0) {  // w_down: 2048*8192 elements
    float c = fmaxf(sm[0] / 16777216.0f, 1e-5f);
    scales[1] = c; scales[3] = 1.0f / c;
  }
}

// ------- ternary weight quant: f32 in -> {-1,0,1} int8 --------
__global__ __launch_bounds__(256) void quant_weight_kernel(
    const float4* __restrict__ w, char8* __restrict__ wq,
    const float* __restrict__ invp, int n8) {
  float inv = *invp;  // 1/clip(mean|w|,1e-5)
  int stride = gridDim.x * 256;
  for (int i = blockIdx.x * 256 + threadIdx.x; i < n8; i += stride) {
    float4 a = w[2 * i], b = w[2 * i + 1];
    float v[8] = {a.x, a.y, a.z, a.w, b.x, b.y, b.z, b.w};
    char8 o;
#pragma unroll
    for (int j = 0; j < 8; ++j) {
      float q = rintf(v[j] * inv);
      q = fminf(fmaxf(q, -1.f), 1.f);
      o[j] = (signed char)(int)q;
    }
    wq[i] = o;
  }
}

// ------- per-token RMSNorm + absmax int8 quant, f32 input (row = 2048) -------
__global__ __launch_bounds__(256) void act_quant_f32_kernel(
    const float* __restrict__ in, signed char* __restrict__ out,
    float* __restrict__ fscale) {
  const int token = blockIdx.x, t = threadIdx.x;
  const float4* row = (const float4*)(in + (size_t)token * 2048);
  float4 a = row[2 * t], b = row[2 * t + 1];
  float v[8] = {a.x, a.y, a.z, a.w, b.x, b.y, b.z, b.w};
  float ss = 0.f, am = 0.f;
#pragma unroll
  for (int j = 0; j < 8; ++j) { ss += v[j] * v[j]; am = fmaxf(am, fabsf(v[j])); }
  __shared__ float s1[256], s2[256];
  s1[t] = ss; s2[t] = am; __syncthreads();
  for (int off = 128; off > 0; off >>= 1) {
    if (t < off) { s1[t] += s1[t + off]; s2[t] = fmaxf(s2[t], s2[t + off]); }
    __syncthreads();
  }
  float r = 1.0f / sqrtf(s1[0] * (1.0f / 2048.0f) + 1e-8f);  // rsqrt(mean+RMS_EPS)
  float f = fmaxf(s2[0] * r, 1e-5f);                          // clip(max|xn|,Q_EPS)
  float s = 127.0f / f;
  if (t == 0) fscale[token] = f * (1.0f / 127.0f);            // dequant factor
  char8 o;
#pragma unroll
  for (int j = 0; j < 8; ++j) {
    float q = rintf((v[j] * r) * s);
    q = fminf(fmaxf(q, -128.f), 127.f);
    o[j] = (signed char)(int)q;
  }
  ((char8*)(out + (size_t)token * 2048))[t] = o;
}

// ------- per-token RMSNorm + absmax int8 quant, fp16 input (row = 8192) -----
__global__ __launch_bounds__(256) void act_quant_h_kernel(
    const _Float16* __restrict__ in, signed char* __restrict__ out,
    float* __restrict__ fscale) {
  const int token = blockIdx.x, t = threadIdx.x;
  const half8* row = (const half8*)(in + (size_t)token * 8192);
  float v[32];
  float ss = 0.f, am = 0.f;
#pragma unroll
  for (int c = 0; c < 4; ++c) {
    half8 u = row[c * 256 + t];
#pragma unroll
    for (int j = 0; j < 8; ++j) {
      float f = (float)u[j]; v[c * 8 + j] = f;
      ss += f * f; am = fmaxf(am, fabsf(f));
    }
  }
  __shared__ float s1[256], s2[256];
  s1[t] = ss; s2[t] = am; __syncthreads();
  for (int off = 128; off > 0; off >>= 1) {
    if (t < off) { s1[t] += s1[t + off]; s2[t] = fmaxf(s2[t], s2[t + off]); }
    __syncthreads();
  }
  float r = 1.0f / sqrtf(s1[0] * (1.0f / 8192.0f) + 1e-8f);
  float f = fmaxf(s2[0] * r, 1e-5f);
  float s = 127.0f / f;
  if (t == 0) fscale[token] = f * (1.0f / 127.0f);
#pragma unroll
  for (int c = 0; c < 4; ++c) {
    char8 o;
#pragma unroll
    for (int j = 0; j < 8; ++j) {
      float q = rintf((v[c * 8 + j] * r) * s);
      q = fminf(fmaxf(q, -128.f), 127.f);
      o[j] = (signed char)(int)q;
    }
    ((char8*)(out + (size_t)token * 8192))[c * 256 + t] = o;
  }
}

// ---------------- GEMM1: z = silu(Xq@WgT[:I]) * (Xq@WgT[I:]) ----------------
// block: 256 tokens x 128 z-cols (= 128 gate rows + 128 value rows of B).
// 8 waves 2Mx4N: wave = 128 rows x 32 z-cols (gate + value accs).
// LDS buffer (32KB): A slabs 0..15 (rows t0+16s), B gate slabs 0..7
// (rows n0+16g), value slabs 8..15 (rows I+n0+16v). Slab = 1024B, slot l =
// row s*16+(l&15), bytes (l>>4)*16..+15 -> frag read = base + l*16.
__global__ __launch_bounds__(512, 2) void gemm1_kernel(
    const signed char* __restrict__ A,  // xq [8192,2048] i8
    const signed char* __restrict__ B,  // wgq [16384,2048] i8 ternary
    const float* __restrict__ f1, const float* __restrict__ cgp,
    _Float16* __restrict__ Z) {         // z fp16 [8192,8192]
  constexpr int K = 2048, I = 8192, NT = K / 64;
  constexpr int ASZ = 16384, BUF = 32768;
  __shared__ __align__(16) signed char Ls[3 * BUF];
  const int t0 = blockIdx.y * 256, n0 = blockIdx.x * 128;
  const int tid = threadIdx.x, w = tid >> 6, l = tid & 63;
  const int wr = w >> 2, wc = w & 3;
  const int lrow = l & 15, lchunk = (l >> 4) * 16;

  int4v ag[8][2], av[8][2];
#pragma unroll
  for (int i = 0; i < 8; ++i)
#pragma unroll
    for (int j = 0; j < 2; ++j) { ag[i][j] = {0,0,0,0}; av[i][j] = {0,0,0,0}; }

  // staging: 32 slabs/K-tile; wave w owns A slabs {w, w+8}, gate w, value w
  const signed char* src[4];
  int dst[4];
  src[0] = A + (size_t)(t0 + w * 16 + lrow) * K + lchunk;       dst[0] = w * 1024;
  src[1] = A + (size_t)(t0 + (w + 8) * 16 + lrow) * K + lchunk; dst[1] = (w + 8) * 1024;
  src[2] = B + (size_t)(n0 + w * 16 + lrow) * K + lchunk;       dst[2] = ASZ + w * 1024;
  src[3] = B + (size_t)(I + n0 + w * 16 + lrow) * K + lchunk;   dst[3] = ASZ + (8 + w) * 1024;

  // prologue: stage tiles 0 and 1 (8 loads/wave in flight)
#pragma unroll
  for (int p = 0; p < 2; ++p)
#pragma unroll
    for (int r = 0; r < 4; ++r) glds16(src[r] + p * 64, &Ls[p * BUF + dst[r]]);
  asm volatile("s_waitcnt vmcnt(4)" ::: "memory");  // tile 0 landed
  __builtin_amdgcn_s_barrier();
  SB0();

  const int abase = (8 * wr) * 1024 + l * 16;           // af[i] = +i*1024
  const int gbase = ASZ + (2 * wc) * 1024 + l * 16;     // bg[j] = +j*1024
  const int vbase = ASZ + (8 + 2 * wc) * 1024 + l * 16; // bv[j] = +j*1024

  int curo = 0;
  for (int it = 0; it < NT; ++it) {
    int stgo = curo + 2 * BUF; if (stgo >= 3 * BUF) stgo -= 3 * BUF;
    const bool stg = (it + 2 < NT);
    const int ko = (it + 2) * 64;
    int4v bg0, bg1, bv0, bv1;

#pragma unroll
    for (int q = 0; q < 4; ++q) {
      // ---- phase q: reads + 1 staging load, then 8 MFMA (quadrant q) ----
      int4v a0 = *(const int4v*)&Ls[curo + abase + (2 * q) * 1024];
      int4v a1 = *(const int4v*)&Ls[curo + abase + (2 * q + 1) * 1024];
      if (q == 0) {
        bg0 = *(const int4v*)&Ls[curo + gbase];
        bg1 = *(const int4v*)&Ls[curo + gbase + 1024];
        bv0 = *(const int4v*)&Ls[curo + vbase];
        bv1 = *(const int4v*)&Ls[curo + vbase + 1024];
      }
      if (stg) glds16(src[q] + ko, &Ls[stgo + dst[q]]);
      SB0();
      __builtin_amdgcn_s_barrier();
      asm volatile("s_waitcnt lgkmcnt(0)" ::: "memory");
      SB0();
      __builtin_amdgcn_s_setprio(1);
      ag[2*q  ][0] = __builtin_amdgcn_mfma_i32_16x16x64_i8(a0, bg0, ag[2*q  ][0], 0, 0, 0);
      ag[2*q  ][1] = __builtin_amdgcn_mfma_i32_16x16x64_i8(a0, bg1, ag[2*q  ][1], 0, 0, 0);
      av[2*q  ][0] = __builtin_amdgcn_mfma_i32_16x16x64_i8(a0, bv0, av[2*q  ][0], 0, 0, 0);
      av[2*q  ][1] = __builtin_amdgcn_mfma_i32_16x16x64_i8(a0, bv1, av[2*q  ][1], 0, 0, 0);
      ag[2*q+1][0] = __builtin_amdgcn_mfma_i32_16x16x64_i8(a1, bg0, ag[2*q+1][0], 0, 0, 0);
      ag[2*q+1][1] = __builtin_amdgcn_mfma_i32_16x16x64_i8(a1, bg1, ag[2*q+1][1], 0, 0, 0);
      av[2*q+1][0] = __builtin_amdgcn_mfma_i32_16x16x64_i8(a1, bv0, av[2*q+1][0], 0, 0, 0);
      av[2*q+1][1] = __builtin_amdgcn_mfma_i32_16x16x64_i8(a1, bv1, av[2*q+1][1], 0, 0, 0);
      __builtin_amdgcn_s_setprio(0);
      SB0();
      if (q < 3) {
        __builtin_amdgcn_s_barrier();
        SB0();
      }
    }
    // ---- K-tile boundary: counted wait (tile it+1 landed), publish ----
    if (it < NT - 2) asm volatile("s_waitcnt vmcnt(4)" ::: "memory");
    else             asm volatile("s_waitcnt vmcnt(0)" ::: "memory");
    __builtin_amdgcn_s_barrier();
    SB0();
    curo += BUF; if (curo == 3 * BUF) curo = 0;
  }

  float cg = *cgp;
#pragma unroll
  for (int i = 0; i < 8; ++i)
#pragma unroll
    for (int rr = 0; rr < 4; ++rr) {
      int m = 128 * wr + i * 16 + (l >> 4) * 4 + rr;
      float fs = f1[t0 + m] * cg;
#pragma unroll
      for (int j = 0; j < 2; ++j) {
        int n = 32 * wc + j * 16 + (l & 15);
        float g = (float)ag[i][j][rr] * fs, vv = (float)av[i][j][rr] * fs;
        float z = g / (1.0f + __expf(-g)) * vv;  // silu(g)*v
        Z[(size_t)(t0 + m) * I + n0 + n] = (_Float16)z;
      }
    }
}

// ---------------- GEMM2: out = (Zq @ WdT) * f2 * cd  (f32 output) ----------
// block: 256 tokens x 256 out-cols; 8 waves 2Mx4N, wave = 128x64.
// Same 3-buffer 4-phase counted-vmcnt pipeline as gemm1.
__global__ __launch_bounds__(512, 2) void gemm2_kernel(
    const signed char* __restrict__ A,  // zq [8192,8192] i8
    const signed char* __restrict__ B,  // wdq [2048,8192] i8 ternary
    const float* __restrict__ f2, const float* __restrict__ cdp,
    float* __restrict__ out) {          // [8192,2048] f32
  constexpr int K = 8192, N = 2048, NT = K / 64;
  constexpr int ASZ = 16384, BUF = 32768;
  __shared__ __align__(16) signed char Ls[3 * BUF];
  const int t0 = blockIdx.y * 256, n0 = blockIdx.x * 256;
  const int tid = threadIdx.x, w = tid >> 6, l = tid & 63;
  const int wr = w >> 2, wc = w & 3;
  const int lrow = l & 15, lchunk = (l >> 4) * 16;

  int4v acc[8][4];
#pragma unroll
  for (int i = 0; i < 8; ++i)
#pragma unroll
    for (int j = 0; j < 4; ++j) acc[i][j] = {0,0,0,0};

  // staging: 32 slabs/K-tile; wave w owns A slabs {w, w+8}, B slabs {w, w+8}
  const signed char* src[4];
  int dst[4];
  src[0] = A + (size_t)(t0 + w * 16 + lrow) * K + lchunk;       dst[0] = w * 1024;
  src[1] = A + (size_t)(t0 + (w + 8) * 16 + lrow) * K + lchunk; dst[1] = (w + 8) * 1024;
  src[2] = B + (size_t)(n0 + w * 16 + lrow) * K + lchunk;       dst[2] = ASZ + w * 1024;
  src[3] = B + (size_t)(n0 + (w + 8) * 16 + lrow) * K + lchunk; dst[3] = ASZ + (w + 8) * 1024;

  // prologue: stage tiles 0 and 1
#pragma unroll
  for (int p = 0; p < 2; ++p)
#pragma unroll
    for (int r = 0; r < 4; ++r) glds16(src[r] + p * 64, &Ls[p * BUF + dst[r]]);
  asm volatile("s_waitcnt vmcnt(4)" ::: "memory");
  __builtin_amdgcn_s_barrier();
  SB0();

  const int abase = (8 * wr) * 1024 + l * 16;        // af[i] = +i*1024
  const int bbase = ASZ + (4 * wc) * 1024 + l * 16;  // bf[j] = +j*1024

  int curo = 0;
  for (int it = 0; it < NT; ++it) {
    int stgo = curo + 2 * BUF; if (stgo >= 3 * BUF) stgo -= 3 * BUF;
    const bool stg = (it + 2 < NT);
    const int ko = (it + 2) * 64;
    int4v bf0, bf1, bf2, bf3;

#pragma unroll
    for (int q = 0; q < 4; ++q) {
      int4v a0 = *(const int4v*)&Ls[curo + abase + (2 * q) * 1024];
      int4v a1 = *(const int4v*)&Ls[curo + abase + (2 * q + 1) * 1024];
      if (q == 0) {
        bf0 = *(const int4v*)&Ls[curo + bbase];
        bf1 = *(const int4v*)&Ls[curo + bbase + 1024];
        bf2 = *(const int4v*)&Ls[curo + bbase + 2048];
        bf3 = *(const int4v*)&Ls[curo + bbase + 3072];
      }
      if (stg) glds16(src[q] + ko, &Ls[stgo + dst[q]]);
      SB0();
      __builtin_amdgcn_s_barrier();
      asm volatile("s_waitcnt lgkmcnt(0)" ::: "memory");
      SB0();
      __builtin_amdgcn_s_setprio(1);
      acc[2*q  ][0] = __builtin_amdgcn_mfma_i32_16x16x64_i8(a0, bf0, acc[2*q  ][0], 0, 0, 0);
      acc[2*q  ][1] = __builtin_amdgcn_mfma_i32_16x16x64_i8(a0, bf1, acc[2*q  ][1], 0, 0, 0);
      acc[2*q  ][2] = __builtin_amdgcn_mfma_i32_16x16x64_i8(a0, bf2, acc[2*q  ][2], 0, 0, 0);
      acc[2*q  ][3] = __builtin_amdgcn_mfma_i32_16x16x64_i8(a0, bf3, acc[2*q  ][3], 0, 0, 0);
      acc[2*q+1][0] = __builtin_amdgcn_mfma_i32_16x16x64_i8(a1, bf0, acc[2*q+1][0], 0, 0, 0);
      acc[2*q+1][1] = __builtin_amdgcn_mfma_i32_16x16x64_i8(a1, bf1, acc[2*q+1][1], 0, 0, 0);
      acc[2*q+1][2] = __builtin_amdgcn_mfma_i32_16x16x64_i8(a1, bf2, acc[2*q+1][2], 0, 0, 0);
      acc[2*q+1][3] = __builtin_amdgcn_mfma_i32_16x16x64_i8(a1, bf3, acc[2*q+1][3], 0, 0, 0);
      __builtin_amdgcn_s_setprio(0);
      SB0();
      if (q < 3) {
        __builtin_amdgcn_s_barrier();
        SB0();
      }
    }
    if (it < NT - 2) asm volatile("s_waitcnt vmcnt(4)" ::: "memory");
    else             asm volatile("s_waitcnt vmcnt(0)" ::: "memory");
    __builtin_amdgcn_s_barrier();
    SB0();
    curo += BUF; if (curo == 3 * BUF) curo = 0;
  }

  float cd = *cdp;
#pragma unroll
  for (int i = 0; i < 8; ++i)
#pragma unroll
    for (int rr = 0; rr < 4; ++rr) {
      int m = 128 * wr + i * 16 + (l >> 4) * 4 + rr;
      float fs = f2[t0 + m] * cd;
#pragma unroll
      for (int j = 0; j < 4; ++j) {
        int n = 64 * wc + j * 16 + (l & 15);
        out[(size_t)(t0 + m) * N + n0 + n] = (float)acc[i][j][rr] * fs;
      }
    }
}

extern "C" void kernel_launch(void* const* d_in, const int* in_sizes, int n_in,
                              void* d_out, int out_size, void* d_ws, size_t ws_size,
                              hipStream_t stream) {
  const float* x  = (const float*)d_in[0];  // [8192,2048] f32
  const float* wg = (const float*)d_in[1];  // [16384,2048] f32
  const float* wd = (const float*)d_in[2];  // [2048,8192] f32
  float* out = (float*)d_out;               // [8192,2048] f32

  // workspace layout (~268.5 MB)
  char* ws = (char*)d_ws;
  signed char* wgq = (signed char*)(ws);                 //  33,554,432 B
  signed char* wdq = (signed char*)(ws + 33554432);      //  16,777,216 B
  signed char* xq  = (signed char*)(ws + 50331648);      //  16,777,216 B
  signed char* zq  = (signed char*)(ws + 67108864);      //  67,108,864 B
  _Float16*    z   = (_Float16*)  (ws + 134217728);      // 134,217,728 B
  float* f1     = (float*)(ws + 268435456);              //      32,768 B
  float* f2     = (float*)(ws + 268468224);              //      32,768 B
  float* pf     = (float*)(ws + 268500992);              //       8,192 B
  float* scales = (float*)(ws + 268509184);              //          16 B

  // 1) global mean(|w|) for both weight matrices (deterministic, no atomics)
  reduce_abs_kernel<<<1024, 256, 0, stream>>>((const float4*)wg, pf, 8388608);
  reduce_abs_kernel<<<1024, 256, 0, stream>>>((const float4*)wd, pf + 1024, 4194304);
  finalize_kernel<<<1, 256, 0, stream>>>(pf, scales);

  // 2) ternarize weights, int8-quantize activations
  quant_weight_kernel<<<2048, 256, 0, stream>>>((const float4*)wg, (char8*)wgq, scales + 2, 4194304);
  quant_weight_kernel<<<1024, 256, 0, stream>>>((const float4*)wd, (char8*)wdq, scales + 3, 2097152);
  act_quant_f32_kernel<<<8192, 256, 0, stream>>>(x, xq, f1);

  // 3) GEMM1 (i8) fused with dequant + silu*v -> z (fp16)
  gemm1_kernel<<<dim3(64, 32), 512, 0, stream>>>(xq, wgq, f1, scales, z);

  // 4) quantize z -> zq (i8) + f2
  act_quant_h_kernel<<<8192, 256, 0, stream>>>(z, zq, f2);

  // 5) GEMM2 (i8) fused with dequant -> out (f32)
  gemm2_kernel<<<dim3(8, 32), 512, 0, stream>>>(zq, wdq, f2, scales + 1, out);
}